// Round 5
// baseline (157.774 us; speedup 1.0000x reference)
//
#include <hip/hip_runtime.h>

// LevelLayer fully fused, one persistent kernel, 1024 blocks x 512 thr
// (4 blocks/CU via ~10.7KB LDS + __launch_bounds__(512,8) => 32 waves/CU,
// the occupancy ceiling). Phases: detect -> space FFN -> [BAR A] -> kNN ->
// GIN1 -> [BAR B] -> GIN2 -> out FFN.
// Cross-block data (pos/hA/hB) is written with AGENT-scope relaxed atomic
// stores (cache-bypassing, complete at coherence point) => grid barrier needs
// NO L2 writeback/invalidate fences. Readers use normal loads (lines never
// locally cached -> miss to coherence point, see fresh data).
// Barrier: 32-leaf(x32) + root counter tree, spread flag lines, relaxed poll.
// Outputs in d_out: h[8192*64] | x_emb[8192*4] | ei[2*122880].

#define N_NODES 8192
#define NPE     256
#define KNN     15
#define LAT     64
#define HID     128
#define NK      (N_NODES*KNN)
#define NBLK    1024
#define NTHR    512
#define NPB     8
#define EI0     (N_NODES*LAT + N_NODES*4)

// barrier region (zeroed by hipMemsetAsync each launch)
#define BARA_LEAF 0
#define BARA_ROOT 2048
#define BARA_FLAG 4096
#define BARB_LEAF 8192
#define BARB_ROOT 10240
#define BARB_FLAG 12288
#define BAR_BYTES 16384

#define OFF_HA  BAR_BYTES
#define OFF_HB  (OFF_HA + N_NODES*LAT*4)
#define OFF_POS (OFF_HB + N_NODES*LAT*4)

typedef unsigned short bf16;
typedef unsigned int   u32;
typedef unsigned long long u64;

__device__ __forceinline__ float bf2f(bf16 s) {
    union { u32 u; float f; } v; v.u = ((u32)s) << 16; return v.f;
}
__device__ __forceinline__ bf16 f2bf(float f) {
    union { float f; u32 u; } v; v.f = f;
    u32 u = v.u + 0x7fffu + ((v.u >> 16) & 1u);   // RNE
    return (bf16)(u >> 16);
}
__device__ __forceinline__ float ldf(const void* p, int i, int f32) {
    return f32 ? ((const float*)p)[i] : bf2f(((const bf16*)p)[i]);
}
// agent-scope relaxed atomic store: bypasses local L1/L2, completes at the
// cross-XCD coherence point. vmcnt(0) after these == globally visible.
__device__ __forceinline__ void st_coh(float* p, float v) {
    __hip_atomic_store(p, v, __ATOMIC_RELAXED, __HIP_MEMORY_SCOPE_AGENT);
}

struct KArgs {
    const void* x;
    const void* se1; const void* bse1; const void* se2; const void* bse2;
    const void* g1a; const void* bg1a; const void* g1b; const void* bg1b;
    const void* g2a; const void* bg2a; const void* g2b; const void* bg2b;
    const void* oe1; const void* boe1; const void* oe2; const void* boe2;
    const u32* wdet;                 // d_in[7] = W_g1a raw bits
    float* hA; float* hB; float* pos; int* bar;
    void* out;
};

struct Shm {
    union {
        int   red[NTHR];                                       // detect (2 KB)
        float hid[NPB][LAT];                                   // space mid (2 KB)
        float kpos[NPE * 3];                                   // knn (3 KB)
        struct { float m[NPB*LAT]; float own[NPB*LAT]; float t[NPB*HID]; } g;  // 8 KB
        float st[NPB*LAT];                                     // out mid (2 KB)
    } u;                                                       // 8 KB
    int   snb[NPB*KNN];   // 480 B
    float sh[NPB*LAT];    // 2 KB, gin2 output -> out FFN
    int   flag;
};                        // ~10.7 KB

// Fence-free tree grid barrier (1024 arrivals: 32 leaves x 32 -> root).
// Bounded spin: broken co-residency -> clean wrong answer, never a hang.
__device__ __forceinline__ void gridbar(int* leaf, int* root, int* flags) {
    asm volatile("s_waitcnt vmcnt(0)" ::: "memory");   // all waves: stores acked
    __syncthreads();
    if (threadIdx.x == 0) {
        const int l = blockIdx.x & 31;
        if (__hip_atomic_fetch_add(leaf + l*16, 1, __ATOMIC_RELAXED,
                                   __HIP_MEMORY_SCOPE_AGENT) == 31) {
            if (__hip_atomic_fetch_add(root, 1, __ATOMIC_RELAXED,
                                       __HIP_MEMORY_SCOPE_AGENT) == 31) {
                #pragma unroll
                for (int i = 0; i < 32; i++)
                    __hip_atomic_store(flags + i*16, 1, __ATOMIC_RELAXED,
                                       __HIP_MEMORY_SCOPE_AGENT);
            }
        }
        int guard = 0;
        while (__hip_atomic_load(flags + l*16, __ATOMIC_RELAXED,
                                 __HIP_MEMORY_SCOPE_AGENT) == 0) {
            __builtin_amdgcn_s_sleep(2);
            if (++guard > (1 << 20)) break;            // fail-safe
        }
        __builtin_amdgcn_fence(__ATOMIC_ACQUIRE, "workgroup"); // compiler order
    }
    __syncthreads();
}

// GIN layer: hout = hin + mlp(hin + sum_nbr hin).  NPB=8 nodes/block, 512 thr.
// phase1: 1 elem/thread, 16 rows to named regs then tree-sum.
// phase2: thread=(node-pair, u): 2-node register reuse per weight load.
// phase3: thread=(node, f): scalar stream, relies on 32 waves/CU TLP.
template<bool LAST>
__device__ __forceinline__ void gin_layer(Shm& S, int base, int f32,
        const float* __restrict__ hin, float* hout,
        const void* Wa, const void* ba, const void* Wb, const void* bb,
        void* out)
{
    const int tid = threadIdx.x;
    // phase 1: m = own + sum of 15 neighbors (wave-uniform rows, 256B loads)
    {
        const int n = tid >> 6, f = tid & 63, gi = base + n;
        const int* nb = &S.snb[n*KNN];
        const float own = hin[gi*LAT + f];
        float vv[KNN];
        #pragma unroll
        for (int k = 0; k < KNN; k++) vv[k] = hin[nb[k]*LAT + f];
        float s0 = vv[0] + vv[1],  s1 = vv[2]  + vv[3],  s2 = vv[4]  + vv[5];
        float s3 = vv[6] + vv[7],  s4 = vv[8]  + vv[9],  s5 = vv[10] + vv[11];
        float s6 = vv[12] + vv[13];
        const float acc = own + (((s0 + s1) + (s2 + s3)) + ((s4 + s5) + (s6 + vv[14])));
        S.u.g.m[tid] = acc; S.u.g.own[tid] = own;
    }
    __syncthreads();
    // phase 2: t[8][128] = relu(m @ Wa + ba); thread = (n2=(tid>>7)*2, u=tid&127)
    {
        const int n2 = (tid >> 7) * 2, u = tid & 127;
        float a0 = ldf(ba, u, f32);
        float a1 = a0;
        if (f32) {
            const float* W = (const float*)Wa;
            #pragma unroll 8
            for (int f = 0; f < LAT; f++) {
                const float w = W[f*HID + u];
                a0 = fmaf(S.u.g.m[(n2    )*LAT + f], w, a0);
                a1 = fmaf(S.u.g.m[(n2 + 1)*LAT + f], w, a1);
            }
        } else {
            const bf16* W = (const bf16*)Wa;
            #pragma unroll 8
            for (int f = 0; f < LAT; f++) {
                const float w = bf2f(W[f*HID + u]);
                a0 = fmaf(S.u.g.m[(n2    )*LAT + f], w, a0);
                a1 = fmaf(S.u.g.m[(n2 + 1)*LAT + f], w, a1);
            }
        }
        S.u.g.t[(n2    )*HID + u] = a0 > 0.f ? a0 : 0.f;
        S.u.g.t[(n2 + 1)*HID + u] = a1 > 0.f ? a1 : 0.f;
    }
    __syncthreads();
    // phase 3: g[8][64] = t @ Wb + bb; thread = (q = tid>>6 -> node q; f)
    {
        const int q = tid >> 6, f = tid & 63, gi = base + q;
        float a0 = ldf(bb, f, f32);
        if (f32) {
            const float* W = (const float*)Wb;
            #pragma unroll 8
            for (int u = 0; u < HID; u++)
                a0 = fmaf(S.u.g.t[q*HID + u], W[u*LAT + f], a0);
        } else {
            const bf16* W = (const bf16*)Wb;
            #pragma unroll 8
            for (int u = 0; u < HID; u++)
                a0 = fmaf(S.u.g.t[q*HID + u], bf2f(W[u*LAT + f]), a0);
        }
        const float o0 = S.u.g.own[q*LAT + f] + a0;
        if (!LAST) {
            st_coh(&hout[gi*LAT + f], o0);
        } else {
            S.sh[q*LAT + f] = o0;
            if (f32) ((float*)out)[gi*LAT + f] = o0;    // output 0: final h
            else     ((bf16*)out)[gi*LAT + f] = f2bf(o0);
        }
    }
    __syncthreads();
}

__global__ __launch_bounds__(NTHR, 8) void k_fused(KArgs a)
{
    __shared__ Shm S;
    const int tid = threadIdx.x, blk = blockIdx.x;
    const int base = blk * NPB;

    // ---- P0: dtype detect (16 KB scan of W_g1a; L2-hot)
    {
        int c = 0;
        for (int i = tid; i < 4096; i += NTHR) {
            const u32 x = a.wdet[i];
            c += ((x >> 7)  & 0xffu) >= 0xC8u;   // low half as bf16: |v| >= 2^73
            c += ((x >> 23) & 0xffu) >= 0xC8u;   // high half
        }
        S.u.red[tid] = c;
        __syncthreads();
        for (int s = NTHR/2; s > 0; s >>= 1) {
            if (tid < s) S.u.red[tid] += S.u.red[tid + s];
            __syncthreads();
        }
        if (tid == 0) S.flag = (S.u.red[0] > 64) ? 1 : 0;   // 1 = fp32 inputs
        __syncthreads();
    }
    const int f32 = S.flag;
    __syncthreads();

    // ---- P1: space_emb  h = leaky(x@W1+b1)@W2+b2
    {
        {   // hidden: 1 elem/thread
            const int n = tid >> 6, f = tid & 63, node = base + n;
            float acc = ldf(a.bse1, f, f32);
            #pragma unroll
            for (int i = 0; i < 4; i++)
                acc = fmaf(ldf(a.x, node*4 + i, f32), ldf(a.se1, i*LAT + f, f32), acc);
            acc = acc > 0.f ? acc : 0.01f*acc;              // leaky
            S.u.hid[n][f] = acc;
        }
        __syncthreads();
        // out: thread = (q -> node q; f)
        const int q = tid >> 6, f = tid & 63;
        float a0 = ldf(a.bse2, f, f32);
        if (f32) {
            const float* W = (const float*)a.se2;
            #pragma unroll 8
            for (int j = 0; j < LAT; j++)
                a0 = fmaf(S.u.hid[q][j], W[j*LAT + f], a0);
        } else {
            const bf16* W = (const bf16*)a.se2;
            #pragma unroll 8
            for (int j = 0; j < LAT; j++)
                a0 = fmaf(S.u.hid[q][j], bf2f(W[j*LAT + f]), a0);
        }
        const int n0 = base + q;
        st_coh(&a.hA[n0*LAT + f], a0);
        if (f < 3) st_coh(&a.pos[n0*3 + f], a0);
    }
    gridbar(a.bar + BARA_LEAF/4, a.bar + BARA_ROOT/4, a.bar + BARA_FLAG/4);

    // ---- P2: kNN; exactly one wave per node; nbr kept in LDS
    {
        const int eb = base & ~(NPE - 1);
        for (int i = tid; i < NPE*3; i += NTHR) S.u.kpos[i] = a.pos[(size_t)eb*3 + i];
        __syncthreads();
        const int wave = tid >> 6, lane = tid & 63;
        const int n  = base + wave;
        const int nl = n - eb;
        const float px = S.u.kpos[nl*3], py = S.u.kpos[nl*3+1], pz = S.u.kpos[nl*3+2];
        u64 key[4];
        #pragma unroll
        for (int c = 0; c < 4; c++) {
            const int j = 64*c + lane;
            const float dx = px - S.u.kpos[j*3], dy = py - S.u.kpos[j*3+1],
                        dz = pz - S.u.kpos[j*3+2];
            // match numpy fp32 ((x^2 + y^2) + z^2), contraction suppressed
            float dd = __fmul_rn(dx, dx);
            dd = __fadd_rn(dd, __fmul_rn(dy, dy));
            dd = __fadd_rn(dd, __fmul_rn(dz, dz));
            key[c] = ((u64)__float_as_uint(dd) << 32) | (u32)j;
            if (j == nl) key[c] = ~0ull;                 // exclude self
        }
        // sort 4 candidates ascending: (0,1)(2,3)(0,2)(1,3)(1,2)
        #define CSWAP(A,B) { const u64 x_ = key[A], y_ = key[B]; \
                             key[A] = x_ < y_ ? x_ : y_; key[B] = x_ < y_ ? y_ : x_; }
        CSWAP(0,1) CSWAP(2,3) CSWAP(0,2) CSWAP(1,3) CSWAP(1,2)
        #undef CSWAP
        int myj = 0;                                     // lane k keeps k-th winner
        #pragma unroll
        for (int k = 0; k < KNN; k++) {
            u64 m = key[0];                              // lane-sorted: head is min
            #pragma unroll
            for (int s = 32; s >= 1; s >>= 1) {          // butterfly min, 64 lanes
                const u64 o = __shfl_xor(m, s, 64);
                m = o < m ? o : m;
            }
            if (lane == k) myj = (int)(u32)m;
            const bool hit = (key[0] == m);              // unique j => one holder
            key[0] = hit ? key[1] : key[0];              // pop
            key[1] = hit ? key[2] : key[1];
            key[2] = hit ? key[3] : key[2];
            key[3] = hit ? ~0ull  : key[3];
        }
        if (lane < KNN) {
            const int gj = eb + myj;
            S.snb[(n - base)*KNN + lane] = gj;
            if (f32) {
                float* o = (float*)a.out;
                o[EI0 + n*KNN + lane]      = (float)gj;  // output 2: ei
                o[EI0 + NK + n*KNN + lane] = (float)n;
            } else {
                bf16* o = (bf16*)a.out;
                o[EI0 + n*KNN + lane]      = f2bf((float)gj);
                o[EI0 + NK + n*KNN + lane] = f2bf((float)n);
            }
        }
        __syncthreads();
    }

    // ---- P3: GIN layer 1 (hA -> hB, coherence-point stores)
    gin_layer<false>(S, base, f32, a.hA, a.hB,
                     a.g1a, a.bg1a, a.g1b, a.bg1b, nullptr);
    gridbar(a.bar + BARB_LEAF/4, a.bar + BARB_ROOT/4, a.bar + BARB_FLAG/4);

    // ---- P4: GIN layer 2 (hB -> LDS sh + d_out h)
    gin_layer<true>(S, base, f32, a.hB, nullptr,
                    a.g2a, a.bg2a, a.g2b, a.bg2b, a.out);

    // ---- P5: out_emb FFN from LDS sh (block-local)
    {
        const int q = tid >> 6, f = tid & 63;
        float a0 = ldf(a.boe1, f, f32);
        if (f32) {
            const float* W = (const float*)a.oe1;
            #pragma unroll 8
            for (int j = 0; j < LAT; j++)
                a0 = fmaf(S.sh[q*LAT + j], W[j*LAT + f], a0);
        } else {
            const bf16* W = (const bf16*)a.oe1;
            #pragma unroll 8
            for (int j = 0; j < LAT; j++)
                a0 = fmaf(S.sh[q*LAT + j], bf2f(W[j*LAT + f]), a0);
        }
        a0 = a0 > 0.f ? a0 : 0.01f*a0;                      // leaky
        __syncthreads();                                     // S.u reuse (st)
        S.u.st[q*LAT + f] = a0;
        __syncthreads();
        if (tid < NPB*4) {
            const int n = tid >> 2, ff = tid & 3;
            float acc = ldf(a.boe2, ff, f32);
            for (int j = 0; j < LAT; j++)
                acc = fmaf(S.u.st[n*LAT + j], ldf(a.oe2, j*4 + ff, f32), acc);
            const int xo = N_NODES*LAT + (base + n)*4 + ff;  // output 1: x_emb
            if (f32) ((float*)a.out)[xo] = acc;
            else     ((bf16*)a.out)[xo] = f2bf(acc);
        }
    }
}

extern "C" void kernel_launch(void* const* d_in, const int* in_sizes, int n_in,
                              void* d_out, int out_size, void* d_ws, size_t ws_size,
                              hipStream_t stream)
{
    (void)in_sizes; (void)n_in; (void)out_size; (void)ws_size;
    char* ws = (char*)d_ws;

    KArgs a;
    a.x   = d_in[0];
    a.se1 = d_in[3];  a.bse1 = d_in[4];  a.se2 = d_in[5];  a.bse2 = d_in[6];
    a.g1a = d_in[7];  a.bg1a = d_in[8];  a.g1b = d_in[9];  a.bg1b = d_in[10];
    a.g2a = d_in[11]; a.bg2a = d_in[12]; a.g2b = d_in[13]; a.bg2b = d_in[14];
    a.oe1 = d_in[15]; a.boe1 = d_in[16]; a.oe2 = d_in[17]; a.boe2 = d_in[18];
    a.wdet = (const u32*)d_in[7];
    a.hA  = (float*)(ws + OFF_HA);
    a.hB  = (float*)(ws + OFF_HB);
    a.pos = (float*)(ws + OFF_POS);
    a.bar = (int*)ws;
    a.out = d_out;

    hipMemsetAsync(d_ws, 0, BAR_BYTES, stream);   // zero barrier tree (captured)
    k_fused<<<dim3(NBLK), dim3(NTHR), 0, stream>>>(a);
}